// Round 1
// baseline (293.752 us; speedup 1.0000x reference)
//
#include <hip/hip_runtime.h>
#include <math.h>

// Problem constants
#define TT 9000          // samples per channel
#define DT 300           // crop length
#define KK 64            // crops per channel
#define NB 35            // band bins: rfft bins 7..41
#define KMIN 7
#define NCH 4096         // B*C channels
#define NPAIR (KK * NB)  // 2240 outputs per channel

// GEMM per channel: C[64 x 96] = A[64 x 320] * W[320 x 96]  (16x16x32 bf16 MFMA)
// v2 restructure:
//  - crops pre-gathered into LDS as bf16 rows [64][328] (656 B stride) so each
//    A-fragment is ONE aligned ds_read_b128 (no per-ks cvt, no scalar ds reads)
//  - 6 waves/block: wave (mg, pg) owns crops mg*32..mg*32+31 and bin pair
//    (cos nt=pg, sin nt=pg+3); its 20 W fragments are preloaded ONCE into
//    registers (80 VGPR) -> k-loop has NO global loads (kills the per-ks
//    L2-latency stall + 4x W L2 traffic of v1)
//  - band sum crosses the 3 pg-waves via a tiny LDS partial buffer

typedef __bf16 bf16;
typedef __attribute__((ext_vector_type(8))) __bf16 bf16x8;
typedef __attribute__((ext_vector_type(4))) __bf16 bf16x4;
typedef __attribute__((ext_vector_type(4))) float f32x4;

#define NFRAG_ELEMS (10 * 6 * 64 * 8)   // 30720 bf16 = 61440 B in d_ws

// W table in B-fragment order: flat idx ((kstep*6 + nt)*64 + lane)*8 + j
// B-frag layout (16x16x32): lane l holds B[k = kstep*32 + (l>>4)*8 + j][n = l&15]
__global__ void build_w(bf16* __restrict__ tab) {
    int i = blockIdx.x * blockDim.x + threadIdx.x;
    if (i >= NFRAG_ELEMS) return;
    int j    = i & 7;
    int l    = (i >> 3) & 63;
    int f    = i >> 9;           // frag index = kstep*6 + nt
    int nt   = f % 6;
    int ks   = f / 6;
    int quad = l >> 4;
    int c    = l & 15;
    int k    = ks * 32 + quad * 8 + j;   // time index 0..319
    int jf   = (nt % 3) * 16 + c;        // band bin index 0..47
    float v = 0.0f;
    if (jf <= NB - 1 && k < DT) {
        int bin = jf + KMIN;                       // rfft bin 7..41
        int ph  = (bin * k) % DT;                  // exact integer phase
        float ang = 0.02094395102393195f * (float)ph;  // 2*pi/300 * ph
        v = (nt >= 3) ? sinf(ang) : cosf(ang);
    }
    tab[i] = (bf16)v;
}

#define ROWB 656   // bytes per crop row in LDS: 328 bf16 (320 data + pad), 41*16

__global__ __launch_bounds__(384, 3) void st_mfma(
        const float* __restrict__ input,    // [NCH, TT] fp32
        const int*   __restrict__ offsets,  // [NCH, KK] int32
        const bf16*  __restrict__ tab,      // W in B-frag order
        float*       __restrict__ out) {    // [NCH, KK, NB] fp32
    __shared__ __align__(16) unsigned char cb[KK * ROWB];  // 41984 B, bf16 crops
    __shared__ __align__(16) float part[KK][4];            // band partial sums [crop][pg]
    __shared__ int offs[KK];

    const int bc  = blockIdx.x;
    const int tid = threadIdx.x;

    if (tid < KK) offs[tid] = offsets[bc * KK + tid];
    __syncthreads();

    // ---- gather crops -> bf16 rows in LDS (4 floats per chunk) ----
    // 64 crops * 80 chunks = 5120 chunks; chunks p>=75 are the zero pad 300..319.
    const float* chan = input + (size_t)bc * TT;
#pragma unroll 4
    for (int i = 0; i < 14; ++i) {
        int n = tid + i * 384;
        if (n < KK * 80) {
            int r = n / 80;            // crop (const-divisor magic mul)
            int p = n - r * 80;        // chunk within crop
            float f0 = 0.f, f1 = 0.f, f2 = 0.f, f3 = 0.f;
            if (p < 75) {              // real data: off+299 <= 8999, always in bounds
                const float* gp = chan + offs[r] + p * 4;
                f0 = gp[0]; f1 = gp[1]; f2 = gp[2]; f3 = gp[3];
            }
            bf16x4 v;
            v[0] = (bf16)f0; v[1] = (bf16)f1; v[2] = (bf16)f2; v[3] = (bf16)f3;
            *(bf16x4*)(cb + r * ROWB + p * 8) = v;   // 8B-aligned ds_write_b64
        }
    }

    const int wid  = tid >> 6;
    const int lane = tid & 63;
    const int mg   = wid & 1;    // M-group: crops mg*32 .. mg*32+31 (2 M-tiles)
    const int pg   = wid >> 1;   // bin group: bins pg*16 + c; cos nt=pg, sin nt=pg+3

    // ---- preload this wave's 20 W fragments into registers (once) ----
    // Issued after the gather loads so staging owns the front of the VMEM queue;
    // latency hides under the barrier. Live across the whole k-loop (~80 VGPR).
    bf16x8 wc[10], ws[10];
#pragma unroll
    for (int ks = 0; ks < 10; ++ks) {
        wc[ks] = *(const bf16x8*)(tab + (size_t)((ks * 6 + pg    ) * 64 + lane) * 8);
        ws[ks] = *(const bf16x8*)(tab + (size_t)((ks * 6 + pg + 3) * 64 + lane) * 8);
    }

    __syncthreads();

    const int quad = lane >> 4;
    const int c    = lane & 15;

    // A-frag: lane holds A[m = c][k = ks*32 + quad*8 + j] -> one b128 per (M,ks).
    // Bank math: row stride 656 ≡ 16 (mod 128) -> start bank 4*((c+quad)&7),
    // 8 lanes per 4-bank group = structural minimum (conflict-free).
    const unsigned char* a0p = cb + (mg * 32 + c) * ROWB + quad * 16;
    const unsigned char* a1p = a0p + 16 * ROWB;

    f32x4 acc_c0 = {0.f,0.f,0.f,0.f}, acc_s0 = {0.f,0.f,0.f,0.f};
    f32x4 acc_c1 = {0.f,0.f,0.f,0.f}, acc_s1 = {0.f,0.f,0.f,0.f};

#pragma unroll
    for (int ks = 0; ks < 10; ++ks) {
        bf16x8 a0 = *(const bf16x8*)(a0p + ks * 64);
        bf16x8 a1 = *(const bf16x8*)(a1p + ks * 64);
        acc_c0 = __builtin_amdgcn_mfma_f32_16x16x32_bf16(a0, wc[ks], acc_c0, 0, 0, 0);
        acc_s0 = __builtin_amdgcn_mfma_f32_16x16x32_bf16(a0, ws[ks], acc_s0, 0, 0, 0);
        acc_c1 = __builtin_amdgcn_mfma_f32_16x16x32_bf16(a1, wc[ks], acc_c1, 0, 0, 0);
        acc_s1 = __builtin_amdgcn_mfma_f32_16x16x32_bf16(a1, ws[ks], acc_s1, 0, 0, 0);
    }

    // ---- epilogue: power, per-wave band partials, cross-wave sum, store ----
    // C/D layout: col = lane&15 (bin pg*16+c), row = quad*4 + r (crop within tile).
    // Invalid bins (pg==2, c>2) have zero W cols -> p==0, harmless in the sum.
    float pv[2][4];
#pragma unroll
    for (int m = 0; m < 2; ++m) {
#pragma unroll
        for (int r = 0; r < 4; ++r) {
            float cv = m ? acc_c1[r] : acc_c0[r];
            float sv = m ? acc_s1[r] : acc_s0[r];
            float p  = cv * cv + sv * sv;
            pv[m][r] = p;
            float s = p;
#pragma unroll
            for (int d = 1; d < 16; d <<= 1) s += __shfl_xor(s, d, 64);  // in-quad
            if (c == 0) part[mg * 32 + m * 16 + quad * 4 + r][pg] = s;
        }
    }
    __syncthreads();

    float* ob = out + (size_t)bc * NPAIR;
#pragma unroll
    for (int m = 0; m < 2; ++m) {
#pragma unroll
        for (int r = 0; r < 4; ++r) {
            int crop = mg * 32 + m * 16 + quad * 4 + r;
            f32x4 t = *(const f32x4*)part[crop];        // b128 broadcast read
            float rinv = __builtin_amdgcn_rcpf(t[0] + t[1] + t[2]);
            if (pg < 2 || c < 3)
                ob[crop * 35 + pg * 16 + c] = pv[m][r] * rinv;
        }
    }
}

extern "C" void kernel_launch(void* const* d_in, const int* in_sizes, int n_in,
                              void* d_out, int out_size, void* d_ws, size_t ws_size,
                              hipStream_t stream) {
    const float* input   = (const float*)d_in[0];  // [256,16,9000] fp32
    const int*   offsets = (const int*)d_in[1];    // [256,16,64] int32
    float*       out     = (float*)d_out;          // [256,16,64,35] fp32
    bf16*        tab     = (bf16*)d_ws;            // 61440 B

    // d_ws is re-poisoned before every timed launch -> rebuild table each call.
    build_w<<<(NFRAG_ELEMS + 255) / 256, 256, 0, stream>>>(tab);
    st_mfma<<<NCH, 384, 0, stream>>>(input, offsets, tab, out);
}